// Round 5
// baseline (281.603 us; speedup 1.0000x reference)
//
#include <hip/hip_runtime.h>
#include <hip/hip_bf16.h>
#include <string.h>

typedef __hip_bfloat16 bf16;
typedef __bf16 bf16x8 __attribute__((ext_vector_type(8)));
typedef float f32x4 __attribute__((ext_vector_type(4)));

typedef __attribute__((address_space(1))) void* gas_ptr;
typedef __attribute__((address_space(3))) void* las_ptr;

__device__ __forceinline__ void gload_lds16(const void* g, void* l) {
  __builtin_amdgcn_global_load_lds((gas_ptr)(void*)g, (las_ptr)l, 16, 0, 0);
}

// Inputs confirmed fp32 (rounds 2-4 passed with fp32 path).

// ---------------- quaternion block expansion helper ----------------
__device__ __forceinline__ void qexpand(const float* r, const float* i_, const float* j_,
                                        const float* k_, bf16* dst, int O4, int I4, int taps,
                                        int gid) {
  int C = 4 * I4;
  int o   = gid / (taps * C);
  int rem = gid % (taps * C);
  int tap = rem / C, c = rem % C;
  int br = o / O4, orr = o % O4, bc = c / I4, ic = c % I4;
  const float* srcs[4] = { r, i_, j_, k_ };
  const int   comp[4][4] = { {0,1,2,3}, {1,0,3,2}, {2,3,0,1}, {3,2,1,0} };
  const float sgn [4][4] = { {1,-1,-1,-1}, {1,1,-1,1}, {1,1,1,-1}, {1,-1,1,1} };
  float v = srcs[comp[br][bc]][(size_t)(orr * I4 + ic) * taps + tap];
  dst[gid] = __float2bfloat16(v * sgn[br][bc]);
}

// ---------------- one prep kernel: weight expansion + misc cvt + all zero-inits ----------------
#define N_W1 49152
#define N_W2 1327104
#define N_W3 16384
#define N_BR 396288
#define N_MI 900
#define N_SQ 512
#define N_SR 8192
#define N_PREP (N_W1 + N_W2 + N_W3 + N_BR + N_MI + N_SQ + N_SR)

__global__ void prep(const float* __restrict__ qr, const float* __restrict__ qi,
                     const float* __restrict__ qj, const float* __restrict__ qk,
                     const float* __restrict__ dr, const float* __restrict__ di,
                     const float* __restrict__ dj, const float* __restrict__ dk,
                     const float* __restrict__ pr, const float* __restrict__ pi,
                     const float* __restrict__ pj, const float* __restrict__ pk,
                     const float* __restrict__ qb, const float* __restrict__ db,
                     const float* __restrict__ pb, const float* __restrict__ tp,
                     bf16* __restrict__ W1t, bf16* __restrict__ W2t, bf16* __restrict__ W3t,
                     bf16* __restrict__ q1p, float* __restrict__ misc,
                     float* __restrict__ ssq, float* __restrict__ Sraw) {
  int gid = blockIdx.x * 256 + threadIdx.x;
  if (gid < N_W1) { qexpand(qr, qi, qj, qk, W1t, 96, 32, 1, gid); return; }
  gid -= N_W1;
  if (gid < N_W2) { qexpand(dr, di, dj, dk, W2t, 96, 96, 9, gid); return; }
  gid -= N_W2;
  if (gid < N_W3) { qexpand(pr, pi, pj, pk, W3t, 32, 32, 1, gid); return; }
  gid -= N_W3;
  if (gid < N_BR) {
    int b = gid / (516 * 384);
    int rem = gid % (516 * 384);
    int cell = rem / 384, c = rem % 384;
    int hp, wp;
    if      (cell < 130) { hp = 0;   wp = cell; }
    else if (cell < 260) { hp = 129; wp = cell - 130; }
    else if (cell < 388) { hp = cell - 260 + 1; wp = 0; }
    else                 { hp = cell - 388 + 1; wp = 129; }
    q1p[((size_t)((b * 130 + hp) * 130) + wp) * 384 + c] = __float2bfloat16(0.0f);
    return;
  }
  gid -= N_BR;
  if (gid < N_MI) {
    if (gid < 384)      misc[gid] = qb[gid];
    else if (gid < 768) misc[gid] = db[gid - 384];
    else if (gid < 896) misc[gid] = pb[gid - 768];
    else                misc[gid] = tp[gid - 896];
    return;
  }
  gid -= N_MI;
  if (gid < N_SQ) { ssq[gid] = 0.0f; return; }
  gid -= N_SQ;
  if (gid < N_SR) { Sraw[gid] = 0.0f; return; }
}

// ---------------- GEMM1 fused: x NCHW fp32 -> LDS transpose -> 3 o-tiles; w-split grid ----------------
__global__ __launch_bounds__(256) void gemm_qkv1f(const float* __restrict__ x,
                                                  const bf16* __restrict__ wt,
                                                  const float* __restrict__ bias,
                                                  bf16* __restrict__ out) {
  __shared__ __align__(16) bf16 Axl[4 * 64 * 32];   // [kchunk][w64][c32] 16 KB
  __shared__ __align__(16) bf16 Bl [4 * 128 * 32];  // [kchunk][o][c32]  32 KB
  const int h = blockIdx.x, wh = blockIdx.y, b = blockIdx.z;
  const int tid = threadIdx.x, wid = tid >> 6, lane = tid & 63;
  const int l16 = lane & 15, q = lane >> 4;
  const int wm = (wid & 1) * 32, wn = (wid >> 1) * 64;
  {
    const int c = tid >> 1, seg = tid & 1;
    const float* src = x + ((size_t)(b * 128 + c) << 14) + h * 128 + wh * 64 + seg * 32;
    bf16* dstc = Axl + (c >> 5) * 2048 + (c & 31);
    for (int j = 0; j < 8; ++j) {
      float4 v = *(const float4*)(src + j * 4);
      int w0 = seg * 32 + j * 4;
      dstc[(w0 + 0) * 32] = __float2bfloat16(v.x);
      dstc[(w0 + 1) * 32] = __float2bfloat16(v.y);
      dstc[(w0 + 2) * 32] = __float2bfloat16(v.z);
      dstc[(w0 + 3) * 32] = __float2bfloat16(v.w);
    }
  }
  for (int ot = 0; ot < 3; ++ot) {
    __syncthreads();
    const bf16* bbase = wt + (size_t)ot * 16384;
    for (int i = 0; i < 8; ++i) {
      int ci = wid * 512 + i * 64 + lane;
      int chunk = ci >> 9, rem = ci & 511;
      int o = rem >> 2, part = rem & 3;
      gload_lds16(bbase + o * 128 + chunk * 32 + part * 8, Bl + (size_t)(wid * 512 + i * 64) * 8);
    }
    __syncthreads();
    f32x4 acc[2][4] = {};
    for (int k = 0; k < 4; ++k) {
      bf16x8 af[2], bfr[4];
      for (int mi = 0; mi < 2; ++mi)
        af[mi] = *(const bf16x8*)&Axl[k * 2048 + (wm + mi * 16 + l16) * 32 + q * 8];
      for (int ni = 0; ni < 4; ++ni)
        bfr[ni] = *(const bf16x8*)&Bl[k * 4096 + (wn + ni * 16 + l16) * 32 + q * 8];
      for (int mi = 0; mi < 2; ++mi)
        for (int ni = 0; ni < 4; ++ni)
          acc[mi][ni] = __builtin_amdgcn_mfma_f32_16x16x32_bf16(af[mi], bfr[ni], acc[mi][ni], 0, 0, 0);
    }
    for (int ni = 0; ni < 4; ++ni) {
      int o = ot * 128 + wn + ni * 16 + l16;
      float bv = bias[o];
      for (int mi = 0; mi < 2; ++mi) {
        int w0 = wh * 64 + wm + mi * 16 + q * 4;
        for (int r = 0; r < 4; ++r) {
          int w = w0 + r;
          size_t idx = ((size_t)((b * 130 + h + 1) * 130) + (w + 1)) * 384 + o;
          out[idx] = __float2bfloat16(acc[mi][ni][r] + bv);
        }
      }
    }
  }
}

// ---------------- conv2 v3: 3x3 implicit GEMM, fat stages (all 9 taps / barrier) ----------------
// grid 1536: xcd=lid&7 -> b=xcd&1, h-band=(xcd>>1)*32; slot=lid>>3: h=band+(slot&31), ob=(slot>>5)*64.
// Per c0 (12 stages): stage A (3 image rows x 130 x 32c) + B (9 taps x 64 o x 32c); 288 MFMA/stage.
__global__ __launch_bounds__(256) void conv3x3(const bf16* __restrict__ in,
                                               const bf16* __restrict__ wt,
                                               const float* __restrict__ bias,
                                               bf16* __restrict__ out) {
  __shared__ __align__(16) short Al[3 * 130 * 32];   // 24960 B
  __shared__ __align__(16) short Bl[9 * 64 * 32];    // 36864 B
  const int lid = blockIdx.x;
  const int xcd = lid & 7, slot = lid >> 3;
  const int b = xcd & 1;
  const int h = (xcd >> 1) * 32 + (slot & 31);
  const int ob = (slot >> 5) * 64;
  const int tid = threadIdx.x, wid = tid >> 6, lane = tid & 63;
  const int l16 = lane & 15, q = lane >> 4;
  const int wm = (wid & 1) * 64, wn = (wid >> 1) * 32;
  f32x4 acc[4][2] = {};
  const bf16* abase = in + (size_t)b * 130 * 130 * 384;
  const bf16* bbase = wt + (size_t)ob * 3456;
  for (int c0 = 0; c0 < 384; c0 += 32) {
    __syncthreads();
    // A: 1560 chunks of 16B ([dh][row][4 parts])
    for (int i = 0; i < 6; ++i) {
      int g = (wid * 6 + i) * 64;
      int ci = g + lane;
      int dh = ci / 520, rem = ci % 520;
      int row = rem >> 2, part = rem & 3;
      gload_lds16(abase + ((size_t)(h + dh) * 130 + row) * 384 + c0 + part * 8, &Al[g * 8]);
    }
    if (wid == 0 && lane < 24) {
      int rem = 1536 + lane - 1040;   // dh = 2
      int row = rem >> 2, part = rem & 3;
      gload_lds16(abase + ((size_t)(h + 2) * 130 + row) * 384 + c0 + part * 8, &Al[1536 * 8]);
    }
    // B: 2304 chunks ([tap][o][4 parts])
    for (int i = 0; i < 9; ++i) {
      int g = (wid * 9 + i) * 64;
      int ci = g + lane;
      int tap = ci >> 8, rem = ci & 255;
      int o = rem >> 2, part = rem & 3;
      gload_lds16(bbase + (size_t)o * 3456 + tap * 384 + c0 + part * 8, &Bl[g * 8]);
    }
    __syncthreads();
    for (int dh = 0; dh < 3; ++dh)
      for (int dw = 0; dw < 3; ++dw) {
        bf16x8 af[4], bfr[2];
        for (int mi = 0; mi < 4; ++mi)
          af[mi] = *(const bf16x8*)&Al[(dh * 130 + wm + mi * 16 + l16 + dw) * 32 + q * 8];
        for (int ni = 0; ni < 2; ++ni)
          bfr[ni] = *(const bf16x8*)&Bl[((dh * 3 + dw) * 64 + wn + ni * 16 + l16) * 32 + q * 8];
        for (int mi = 0; mi < 4; ++mi)
          for (int ni = 0; ni < 2; ++ni)
            acc[mi][ni] = __builtin_amdgcn_mfma_f32_16x16x32_bf16(af[mi], bfr[ni], acc[mi][ni], 0, 0, 0);
      }
  }
  for (int ni = 0; ni < 2; ++ni) {
    int o = ob + wn + ni * 16 + l16;
    float bv = bias[o];
    for (int mi = 0; mi < 4; ++mi) {
      int w0 = wm + mi * 16 + q * 4;
      for (int r = 0; r < 4; ++r) {
        int w = w0 + r;
        out[((size_t)(b * 16384 + h * 128 + w)) * 384 + o] = __float2bfloat16(acc[mi][ni][r] + bv);
      }
    }
  }
}

// ---------------- attn_qk + fused channel ssq (LDS-reduced atomics) ----------------
__global__ __launch_bounds__(256) void attn_qk(const bf16* __restrict__ q2,
                                               float* __restrict__ Sraw,
                                               float* __restrict__ ssq) {
  const int sc = blockIdx.x, h = blockIdx.y, b = blockIdx.z;
  const int t = threadIdx.x;
  __shared__ bf16 qt[64][32];
  __shared__ bf16 kt[64][32];
  __shared__ float Sl[1024];
  __shared__ float nql[32], nkl[32];
  for (int i = t; i < 1024; i += 256) Sl[i] = 0.0f;
  if (t < 32) nql[t] = 0.0f;
  else if (t < 64) nkl[t - 32] = 0.0f;
  const int slq = t >> 2, seg = t & 3;
  const int slot = t & 63, sg = t >> 6;
  const int cg = (slot & 7) * 4, dg = (slot >> 3) * 4;
  float acc[4][4] = {};
  float sq[4] = {}, sk[4] = {};
  for (int it = 0; it < 4; ++it) {
    int sbase = sc * 256 + it * 64;
    __syncthreads();
    {
      size_t rq = ((size_t)(b * 16384 + sbase + slq)) * 384 + h * 32 + seg * 8;
      *(bf16x8*)&qt[slq][seg * 8] = *(const bf16x8*)&q2[rq];
      *(bf16x8*)&kt[slq][seg * 8] = *(const bf16x8*)&q2[rq + 128];
    }
    __syncthreads();
    for (int sl = sg * 16; sl < sg * 16 + 16; ++sl) {
      float qv[4], kv[4];
      for (int a = 0; a < 4; ++a) qv[a] = __bfloat162float(qt[sl][cg + a]);
      for (int d = 0; d < 4; ++d) kv[d] = __bfloat162float(kt[sl][dg + d]);
      if (dg == 0) for (int a = 0; a < 4; ++a) sq[a] += qv[a] * qv[a];
      if (cg == 0) for (int d = 0; d < 4; ++d) sk[d] += kv[d] * kv[d];
      for (int a = 0; a < 4; ++a)
        for (int d = 0; d < 4; ++d) acc[a][d] += qv[a] * kv[d];
    }
  }
  for (int a = 0; a < 4; ++a)
    for (int d = 0; d < 4; ++d)
      atomicAdd(&Sl[(cg + a) * 32 + dg + d], acc[a][d]);
  if (dg == 0) for (int a = 0; a < 4; ++a) atomicAdd(&nql[cg + a], sq[a]);
  if (cg == 0) for (int d = 0; d < 4; ++d) atomicAdd(&nkl[dg + d], sk[d]);
  __syncthreads();
  float* Sg = Sraw + (size_t)((b * 4 + h) * 1024);
  for (int i = t * 4; i < t * 4 + 4; ++i) atomicAdd(&Sg[i], Sl[i]);
  if (t < 32) atomicAdd(&ssq[b * 256 + h * 32 + t], nql[t]);
  else if (t < 64) atomicAdd(&ssq[b * 256 + 128 + h * 32 + (t - 32)], nkl[t - 32]);
}

// ---------------- smallM: softmax P, then M = W3 . blockdiag(P) (per b) ----------------
__global__ void smallM(const float* __restrict__ Sraw, const float* __restrict__ ssq,
                       const float* __restrict__ misc, const bf16* __restrict__ w3,
                       bf16* __restrict__ M) {
  const int b = blockIdx.x;
  const int t = threadIdx.x;
  __shared__ float rqa[128], rka[128];
  __shared__ float Pl[4][32][32];
  if (t < 128) rqa[t] = 1.0f / fmaxf(sqrtf(fmaxf(ssq[b * 256 + t], 0.0f)), 1e-12f);
  else rka[t - 128] = 1.0f / fmaxf(sqrtf(fmaxf(ssq[b * 256 + t], 0.0f)), 1e-12f);
  __syncthreads();
  if (t < 128) {
    int hh = t >> 5, c = t & 31;
    const float* Sr = Sraw + ((size_t)((b * 4 + hh) * 32 + c)) * 32;
    float tv = misc[896 + hh];
    float rq = rqa[hh * 32 + c];
    float row[32];
    float m = -1e30f;
    for (int d = 0; d < 32; ++d) { row[d] = Sr[d] * tv * rq * rka[hh * 32 + d]; m = fmaxf(m, row[d]); }
    float sum = 0.0f;
    for (int d = 0; d < 32; ++d) { row[d] = expf(row[d] - m); sum += row[d]; }
    float inv = 1.0f / sum;
    for (int d = 0; d < 32; ++d) Pl[hh][c][d] = row[d] * inv;
  }
  __syncthreads();
  const int o = t >> 1, half = t & 1;
  for (int j = 0; j < 64; ++j) {
    int dg = half * 64 + j;
    int hh = dg >> 5, d = dg & 31;
    float s = 0.0f;
    for (int c = 0; c < 32; ++c)
      s += __bfloat162float(w3[o * 128 + hh * 32 + c]) * Pl[hh][c][d];
    M[(size_t)b * 16384 + o * 128 + dg] = __float2bfloat16(s);
  }
}

// ---------------- gemm_out: out[b][o][s] = M[b] . v + po_b ; v = q2 NHWC cols 256..383 ----------------
__global__ __launch_bounds__(256) void gemm_out(const bf16* __restrict__ q2,
                                                const bf16* __restrict__ M,
                                                const float* __restrict__ bias,
                                                float* __restrict__ out) {
  __shared__ __align__(16) short Al[128 * 32];
  __shared__ __align__(16) short Bl[128 * 32];
  const int tile = blockIdx.x;
  const int b = tile >> 7, s0 = (tile & 127) * 128;
  const int tid = threadIdx.x, wid = tid >> 6, lane = tid & 63;
  const int l16 = lane & 15, q = lane >> 4;
  const int wm = (wid & 1) * 64, wn = (wid >> 1) * 64;
  f32x4 acc[4][4] = {};
  const bf16* Mb = M + (size_t)b * 16384;
  const bf16* vb = q2 + ((size_t)(b * 16384 + s0)) * 384 + 256;
  for (int c0 = 0; c0 < 128; c0 += 32) {
    __syncthreads();
    for (int i = 0; i < 2; ++i) {
      int ci = (wid * 2 + i) * 64 + lane;
      int row = ci >> 2, part = ci & 3;
      gload_lds16(Mb + row * 128 + c0 + part * 8, &Al[(wid * 2 + i) * 512]);
      gload_lds16(vb + (size_t)row * 384 + c0 + part * 8, &Bl[(wid * 2 + i) * 512]);
    }
    __syncthreads();
    bf16x8 af[4], bfr[4];
    for (int mi = 0; mi < 4; ++mi) af[mi]  = *(const bf16x8*)&Al[(wm + mi * 16 + l16) * 32 + q * 8];
    for (int ni = 0; ni < 4; ++ni) bfr[ni] = *(const bf16x8*)&Bl[(wn + ni * 16 + l16) * 32 + q * 8];
    for (int mi = 0; mi < 4; ++mi)
      for (int ni = 0; ni < 4; ++ni)
        acc[mi][ni] = __builtin_amdgcn_mfma_f32_16x16x32_bf16(af[mi], bfr[ni], acc[mi][ni], 0, 0, 0);
  }
  for (int ni = 0; ni < 4; ++ni) {
    int s = s0 + wn + ni * 16 + l16;
    for (int mi = 0; mi < 4; ++mi) {
      int o0 = wm + mi * 16 + q * 4;
      for (int r = 0; r < 4; ++r) {
        int o = o0 + r;
        out[(size_t)b * 2097152 + (size_t)o * 16384 + s] = acc[mi][ni][r] + bias[o];
      }
    }
  }
}

extern "C" void kernel_launch(void* const* d_in, const int* in_sizes, int n_in,
                              void* d_out, int out_size, void* d_ws, size_t ws_size,
                              hipStream_t stream) {
  const float* x     = (const float*)d_in[0];
  const float* qkv_r = (const float*)d_in[1];
  const float* qkv_i = (const float*)d_in[2];
  const float* qkv_j = (const float*)d_in[3];
  const float* qkv_k = (const float*)d_in[4];
  const float* qkv_b = (const float*)d_in[5];
  const float* dw_r  = (const float*)d_in[6];
  const float* dw_i  = (const float*)d_in[7];
  const float* dw_j  = (const float*)d_in[8];
  const float* dw_k  = (const float*)d_in[9];
  const float* dw_b  = (const float*)d_in[10];
  const float* po_r  = (const float*)d_in[11];
  const float* po_i  = (const float*)d_in[12];
  const float* po_j  = (const float*)d_in[13];
  const float* po_k  = (const float*)d_in[14];
  const float* po_b  = (const float*)d_in[15];
  const float* temp  = (const float*)d_in[16];

  char* ws = (char*)d_ws;
  size_t off = 0;
  auto alloc = [&](size_t bytes) { char* p = ws + off; off += (bytes + 255) & ~(size_t)255; return p; };
  bf16* q1p  = (bf16*)alloc((size_t)2 * 130 * 130 * 384 * 2);
  bf16* q2   = (bf16*)alloc((size_t)2 * 16384 * 384 * 2);
  bf16* W1t  = (bf16*)alloc((size_t)384 * 128 * 2);
  bf16* W2t  = (bf16*)alloc((size_t)384 * 3456 * 2);
  bf16* W3t  = (bf16*)alloc((size_t)128 * 128 * 2);
  bf16* Mb   = (bf16*)alloc((size_t)2 * 128 * 128 * 2);
  float* ssq  = (float*)alloc((size_t)2 * 256 * 4);
  float* Sraw = (float*)alloc((size_t)2 * 4 * 32 * 32 * 4);
  float* misc = (float*)alloc((size_t)900 * 4);

  prep<<<(N_PREP + 255) / 256, 256, 0, stream>>>(qkv_r, qkv_i, qkv_j, qkv_k,
                                                 dw_r, dw_i, dw_j, dw_k,
                                                 po_r, po_i, po_j, po_k,
                                                 qkv_b, dw_b, po_b, temp,
                                                 W1t, W2t, W3t, q1p, misc, ssq, Sraw);
  gemm_qkv1f<<<dim3(128, 2, 2), 256, 0, stream>>>(x, W1t, misc, q1p);
  conv3x3<<<1536, 256, 0, stream>>>(q1p, W2t, misc + 384, q2);
  attn_qk<<<dim3(64, 4, 2), 256, 0, stream>>>(q2, Sraw, ssq);
  smallM<<<2, 256, 0, stream>>>(Sraw, ssq, misc, W3t, Mb);
  gemm_out<<<256, 256, 0, stream>>>(q2, Mb, misc + 768, (float*)d_out);
}

// Round 7
// 241.859 us; speedup vs baseline: 1.1643x; 1.1643x over previous
//
#include <hip/hip_runtime.h>
#include <hip/hip_bf16.h>
#include <string.h>

typedef __hip_bfloat16 bf16;
typedef __bf16 bf16x8 __attribute__((ext_vector_type(8)));
typedef float f32x4 __attribute__((ext_vector_type(4)));

typedef __attribute__((address_space(1))) void* gas_ptr;
typedef __attribute__((address_space(3))) void* las_ptr;

__device__ __forceinline__ void gload_lds16(const void* g, void* l) {
  __builtin_amdgcn_global_load_lds((gas_ptr)(void*)g, (las_ptr)l, 16, 0, 0);
}

// Inputs confirmed fp32 (rounds 2-5 passed with fp32 path).

// ---------------- quaternion block expansion helper ----------------
__device__ __forceinline__ void qexpand(const float* r, const float* i_, const float* j_,
                                        const float* k_, bf16* dst, int O4, int I4, int taps,
                                        int gid) {
  int C = 4 * I4;
  int o   = gid / (taps * C);
  int rem = gid % (taps * C);
  int tap = rem / C, c = rem % C;
  int br = o / O4, orr = o % O4, bc = c / I4, ic = c % I4;
  const float* srcs[4] = { r, i_, j_, k_ };
  const int   comp[4][4] = { {0,1,2,3}, {1,0,3,2}, {2,3,0,1}, {3,2,1,0} };
  const float sgn [4][4] = { {1,-1,-1,-1}, {1,1,-1,1}, {1,1,1,-1}, {1,-1,1,1} };
  float v = srcs[comp[br][bc]][(size_t)(orr * I4 + ic) * taps + tap];
  dst[gid] = __float2bfloat16(v * sgn[br][bc]);
}

// ---------------- one prep kernel: weight expansion + misc cvt + all zero-inits ----------------
#define N_W1 49152
#define N_W2 1327104
#define N_W3 16384
#define N_BR 396288
#define N_MI 900
#define N_SQ 512
#define N_SR 8192
#define N_PREP (N_W1 + N_W2 + N_W3 + N_BR + N_MI + N_SQ + N_SR)

__global__ void prep(const float* __restrict__ qr, const float* __restrict__ qi,
                     const float* __restrict__ qj, const float* __restrict__ qk,
                     const float* __restrict__ dr, const float* __restrict__ di,
                     const float* __restrict__ dj, const float* __restrict__ dk,
                     const float* __restrict__ pr, const float* __restrict__ pi,
                     const float* __restrict__ pj, const float* __restrict__ pk,
                     const float* __restrict__ qb, const float* __restrict__ db,
                     const float* __restrict__ pb, const float* __restrict__ tp,
                     bf16* __restrict__ W1t, bf16* __restrict__ W2t, bf16* __restrict__ W3t,
                     bf16* __restrict__ q1p, float* __restrict__ misc,
                     float* __restrict__ ssq, float* __restrict__ Sraw) {
  int gid = blockIdx.x * 256 + threadIdx.x;
  if (gid < N_W1) { qexpand(qr, qi, qj, qk, W1t, 96, 32, 1, gid); return; }
  gid -= N_W1;
  if (gid < N_W2) { qexpand(dr, di, dj, dk, W2t, 96, 96, 9, gid); return; }
  gid -= N_W2;
  if (gid < N_W3) { qexpand(pr, pi, pj, pk, W3t, 32, 32, 1, gid); return; }
  gid -= N_W3;
  if (gid < N_BR) {
    int b = gid / (516 * 384);
    int rem = gid % (516 * 384);
    int cell = rem / 384, c = rem % 384;
    int hp, wp;
    if      (cell < 130) { hp = 0;   wp = cell; }
    else if (cell < 260) { hp = 129; wp = cell - 130; }
    else if (cell < 388) { hp = cell - 260 + 1; wp = 0; }
    else                 { hp = cell - 388 + 1; wp = 129; }
    q1p[((size_t)((b * 130 + hp) * 130) + wp) * 384 + c] = __float2bfloat16(0.0f);
    return;
  }
  gid -= N_BR;
  if (gid < N_MI) {
    if (gid < 384)      misc[gid] = qb[gid];
    else if (gid < 768) misc[gid] = db[gid - 384];
    else if (gid < 896) misc[gid] = pb[gid - 768];
    else                misc[gid] = tp[gid - 896];
    return;
  }
  gid -= N_MI;
  if (gid < N_SQ) { ssq[gid] = 0.0f; return; }
  gid -= N_SQ;
  if (gid < N_SR) { Sraw[gid] = 0.0f; return; }
}

// ---------------- GEMM1 fused: x NCHW fp32 -> LDS transpose -> 3 o-tiles; w-split grid ----------------
__global__ __launch_bounds__(256) void gemm_qkv1f(const float* __restrict__ x,
                                                  const bf16* __restrict__ wt,
                                                  const float* __restrict__ bias,
                                                  bf16* __restrict__ out) {
  __shared__ __align__(16) bf16 Axl[4 * 64 * 32];   // [kchunk][w64][c32] 16 KB
  __shared__ __align__(16) bf16 Bl [4 * 128 * 32];  // [kchunk][o][c32]  32 KB
  const int h = blockIdx.x, wh = blockIdx.y, b = blockIdx.z;
  const int tid = threadIdx.x, wid = tid >> 6, lane = tid & 63;
  const int l16 = lane & 15, q = lane >> 4;
  const int wm = (wid & 1) * 32, wn = (wid >> 1) * 64;
  {
    const int c = tid >> 1, seg = tid & 1;
    const float* src = x + ((size_t)(b * 128 + c) << 14) + h * 128 + wh * 64 + seg * 32;
    bf16* dstc = Axl + (c >> 5) * 2048 + (c & 31);
    for (int j = 0; j < 8; ++j) {
      float4 v = *(const float4*)(src + j * 4);
      int w0 = seg * 32 + j * 4;
      dstc[(w0 + 0) * 32] = __float2bfloat16(v.x);
      dstc[(w0 + 1) * 32] = __float2bfloat16(v.y);
      dstc[(w0 + 2) * 32] = __float2bfloat16(v.z);
      dstc[(w0 + 3) * 32] = __float2bfloat16(v.w);
    }
  }
  for (int ot = 0; ot < 3; ++ot) {
    __syncthreads();
    const bf16* bbase = wt + (size_t)ot * 16384;
    for (int i = 0; i < 8; ++i) {
      int ci = wid * 512 + i * 64 + lane;
      int chunk = ci >> 9, rem = ci & 511;
      int o = rem >> 2, part = rem & 3;
      gload_lds16(bbase + o * 128 + chunk * 32 + part * 8, Bl + (size_t)(wid * 512 + i * 64) * 8);
    }
    __syncthreads();
    f32x4 acc[2][4] = {};
    for (int k = 0; k < 4; ++k) {
      bf16x8 af[2], bfr[4];
      for (int mi = 0; mi < 2; ++mi)
        af[mi] = *(const bf16x8*)&Axl[k * 2048 + (wm + mi * 16 + l16) * 32 + q * 8];
      for (int ni = 0; ni < 4; ++ni)
        bfr[ni] = *(const bf16x8*)&Bl[k * 4096 + (wn + ni * 16 + l16) * 32 + q * 8];
      for (int mi = 0; mi < 2; ++mi)
        for (int ni = 0; ni < 4; ++ni)
          acc[mi][ni] = __builtin_amdgcn_mfma_f32_16x16x32_bf16(af[mi], bfr[ni], acc[mi][ni], 0, 0, 0);
    }
    for (int ni = 0; ni < 4; ++ni) {
      int o = ot * 128 + wn + ni * 16 + l16;
      float bv = bias[o];
      for (int mi = 0; mi < 2; ++mi) {
        int w0 = wh * 64 + wm + mi * 16 + q * 4;
        for (int r = 0; r < 4; ++r) {
          int w = w0 + r;
          size_t idx = ((size_t)((b * 130 + h + 1) * 130) + (w + 1)) * 384 + o;
          out[idx] = __float2bfloat16(acc[mi][ni][r] + bv);
        }
      }
    }
  }
}

// ---------------- conv2 v4: 4 h-rows/block share halo A; 64-w half; 64-o slice ----------------
__global__ __launch_bounds__(256) void conv3x3(const bf16* __restrict__ in,
                                               const bf16* __restrict__ wt,
                                               const float* __restrict__ bias,
                                               bf16* __restrict__ out) {
  __shared__ __align__(16) short Al[6 * 66 * 32];   // 25344 B
  __shared__ __align__(16) short Bl[9 * 64 * 32];   // 36864 B
  const int lid = blockIdx.x;
  const int xcd = lid & 7, slot = lid >> 3;
  const int b = xcd & 1;
  const int h0 = (xcd >> 1) * 32 + (slot & 7) * 4;
  const int wh = (slot >> 3) & 1;
  const int ob = (slot >> 4) * 64;
  const int tid = threadIdx.x, wid = tid >> 6, lane = tid & 63;
  const int l16 = lane & 15, q = lane >> 4;
  f32x4 acc[4][4] = {};
  const bf16* abase = in + (size_t)b * 130 * 130 * 384 + (size_t)wh * 64 * 384;
  const bf16* bbase = wt + (size_t)ob * 3456;
  for (int c0 = 0; c0 < 384; c0 += 32) {
    __syncthreads();
    // A: 1584 chunks: ci -> row=ci/264, w=(ci%264)>>2, part=ci&3
    for (int i = 0; i < 6; ++i) {
      int g = (wid * 6 + i) * 64;
      int ci = g + lane;
      int row = ci / 264, rem = ci % 264;
      int w = rem >> 2, part = rem & 3;
      gload_lds16(abase + ((size_t)(h0 + row) * 130 + w) * 384 + c0 + part * 8, &Al[g * 8]);
    }
    if (wid == 0 && lane < 48) {
      int ci = 1536 + lane;
      int row = ci / 264, rem = ci % 264;
      int w = rem >> 2, part = rem & 3;
      gload_lds16(abase + ((size_t)(h0 + row) * 130 + w) * 384 + c0 + part * 8, &Al[1536 * 8]);
    }
    // B: 2304 chunks ([tap][o][4 parts])
    for (int i = 0; i < 9; ++i) {
      int g = (wid * 9 + i) * 64;
      int ci = g + lane;
      int tap = ci >> 8, rem = ci & 255;
      int o = rem >> 2, part = rem & 3;
      gload_lds16(bbase + (size_t)o * 3456 + tap * 384 + c0 + part * 8, &Bl[g * 8]);
    }
    __syncthreads();
    for (int dh = 0; dh < 3; ++dh)
      for (int dw = 0; dw < 3; ++dw) {
        bf16x8 af[4], bfr[4];
        for (int mi = 0; mi < 4; ++mi)
          af[mi] = *(const bf16x8*)&Al[((wid + dh) * 66 + mi * 16 + l16 + dw) * 32 + q * 8];
        for (int ni = 0; ni < 4; ++ni)
          bfr[ni] = *(const bf16x8*)&Bl[((dh * 3 + dw) * 64 + ni * 16 + l16) * 32 + q * 8];
        for (int mi = 0; mi < 4; ++mi)
          for (int ni = 0; ni < 4; ++ni)
            acc[mi][ni] = __builtin_amdgcn_mfma_f32_16x16x32_bf16(af[mi], bfr[ni], acc[mi][ni], 0, 0, 0);
      }
  }
  const int h = h0 + wid;
  for (int ni = 0; ni < 4; ++ni) {
    int o = ob + ni * 16 + l16;
    float bv = bias[o];
    for (int mi = 0; mi < 4; ++mi) {
      int w0 = wh * 64 + mi * 16 + q * 4;
      for (int r = 0; r < 4; ++r) {
        int w = w0 + r;
        out[((size_t)(b * 16384 + h * 128 + w)) * 384 + o] = __float2bfloat16(acc[mi][ni][r] + bv);
      }
    }
  }
}

// ---------------- attn_qk + fused channel ssq (LDS-reduced atomics) ----------------
__global__ __launch_bounds__(256) void attn_qk(const bf16* __restrict__ q2,
                                               float* __restrict__ Sraw,
                                               float* __restrict__ ssq) {
  const int sc = blockIdx.x, h = blockIdx.y, b = blockIdx.z;
  const int t = threadIdx.x;
  __shared__ bf16 qt[64][32];
  __shared__ bf16 kt[64][32];
  __shared__ float Sl[1024];
  __shared__ float nql[32], nkl[32];
  for (int i = t; i < 1024; i += 256) Sl[i] = 0.0f;
  if (t < 32) nql[t] = 0.0f;
  else if (t < 64) nkl[t - 32] = 0.0f;
  const int slq = t >> 2, seg = t & 3;
  const int slot = t & 63, sg = t >> 6;
  const int cg = (slot & 7) * 4, dg = (slot >> 3) * 4;
  float acc[4][4] = {};
  float sq[4] = {}, sk[4] = {};
  for (int it = 0; it < 4; ++it) {
    int sbase = sc * 256 + it * 64;
    __syncthreads();
    {
      size_t rq = ((size_t)(b * 16384 + sbase + slq)) * 384 + h * 32 + seg * 8;
      *(bf16x8*)&qt[slq][seg * 8] = *(const bf16x8*)&q2[rq];
      *(bf16x8*)&kt[slq][seg * 8] = *(const bf16x8*)&q2[rq + 128];
    }
    __syncthreads();
    for (int sl = sg * 16; sl < sg * 16 + 16; ++sl) {
      float qv[4], kv[4];
      for (int a = 0; a < 4; ++a) qv[a] = __bfloat162float(qt[sl][cg + a]);
      for (int d = 0; d < 4; ++d) kv[d] = __bfloat162float(kt[sl][dg + d]);
      if (dg == 0) for (int a = 0; a < 4; ++a) sq[a] += qv[a] * qv[a];
      if (cg == 0) for (int d = 0; d < 4; ++d) sk[d] += kv[d] * kv[d];
      for (int a = 0; a < 4; ++a)
        for (int d = 0; d < 4; ++d) acc[a][d] += qv[a] * kv[d];
    }
  }
  for (int a = 0; a < 4; ++a)
    for (int d = 0; d < 4; ++d)
      atomicAdd(&Sl[(cg + a) * 32 + dg + d], acc[a][d]);
  if (dg == 0) for (int a = 0; a < 4; ++a) atomicAdd(&nql[cg + a], sq[a]);
  if (cg == 0) for (int d = 0; d < 4; ++d) atomicAdd(&nkl[dg + d], sk[d]);
  __syncthreads();
  float* Sg = Sraw + (size_t)((b * 4 + h) * 1024);
  for (int i = t * 4; i < t * 4 + 4; ++i) atomicAdd(&Sg[i], Sl[i]);
  if (t < 32) atomicAdd(&ssq[b * 256 + h * 32 + t], nql[t]);
  else if (t < 64) atomicAdd(&ssq[b * 256 + 128 + h * 32 + (t - 32)], nkl[t - 32]);
}

// ---------------- attn_out: softmax -> M = W3.blockdiag(P) in LDS -> GEMM vs v -> d_out ----------------
__global__ __launch_bounds__(256) void attn_out(const bf16* __restrict__ q2,
                                                const float* __restrict__ Sraw,
                                                const float* __restrict__ ssq,
                                                const float* __restrict__ misc,
                                                const bf16* __restrict__ w3,
                                                float* __restrict__ out) {
  __shared__ __align__(16) bf16 Ml[4 * 128 * 32];   // 32 KB [kchunk][o][c31]
  __shared__ float Pl[4][32][32];                    // 16 KB
  __shared__ __align__(16) short Bl[128 * 32];       // 8 KB v-stage
  __shared__ float rqa[128], rka[128];
  const int tile = blockIdx.x;
  const int b = tile >> 7, s0 = (tile & 127) * 128;
  const int t = threadIdx.x;
  const int wid = t >> 6, lane = t & 63;
  const int l16 = lane & 15, q = lane >> 4;
  {
    float v = ssq[b * 256 + t];
    float rv = 1.0f / fmaxf(sqrtf(fmaxf(v, 0.0f)), 1e-12f);
    if (t < 128) rqa[t] = rv; else rka[t - 128] = rv;
  }
  __syncthreads();
  if (t < 128) {
    int hh = t >> 5, c = t & 31;
    const float* Sr = Sraw + ((size_t)((b * 4 + hh) * 32 + c)) * 32;
    float tv = misc[896 + hh];
    float rq = rqa[t];
    float row[32];
    float m = -1e30f;
    for (int d = 0; d < 32; ++d) { row[d] = Sr[d] * tv * rq * rka[hh * 32 + d]; m = fmaxf(m, row[d]); }
    float sum = 0.0f;
    for (int d = 0; d < 32; ++d) { row[d] = expf(row[d] - m); sum += row[d]; }
    float inv = 1.0f / sum;
    for (int d = 0; d < 32; ++d) Pl[hh][c][d] = row[d] * inv;
  }
  __syncthreads();
  {
    const int o = t >> 1, half = t & 1;
    for (int hh2 = 0; hh2 < 2; ++hh2) {
      int hv = half * 2 + hh2;
      float w3r[32];
      const bf16* wrow = w3 + o * 128 + hv * 32;
      for (int c = 0; c < 32; ++c) w3r[c] = __bfloat162float(wrow[c]);
      for (int d = 0; d < 32; ++d) {
        float s = 0.0f;
        for (int c = 0; c < 32; ++c) s += w3r[c] * Pl[hv][c][d];
        Ml[hv * 4096 + o * 32 + d] = __float2bfloat16(s);
      }
    }
  }
  f32x4 acc[4][4] = {};
  const int wmo = (wid & 1) * 64, wns = (wid >> 1) * 64;
  for (int kc = 0; kc < 4; ++kc) {
    __syncthreads();
    for (int i = 0; i < 2; ++i) {
      int ci = i * 256 + t;                         // t = wid*64 + lane
      int s = ci >> 2, part = ci & 3;
      // LDS dest = wave-uniform base + lane*16: fold wid into the base! (round-6 bug)
      gload_lds16(q2 + ((size_t)(b * 16384 + s0 + s)) * 384 + 256 + kc * 32 + part * 8,
                  &Bl[(size_t)(i * 256 + wid * 64) * 8]);
    }
    __syncthreads();
    bf16x8 af[4], bfr[4];
    for (int mi = 0; mi < 4; ++mi)
      af[mi] = *(const bf16x8*)&Ml[kc * 4096 + (wmo + mi * 16 + l16) * 32 + q * 8];
    for (int ni = 0; ni < 4; ++ni)
      bfr[ni] = *(const bf16x8*)&Bl[(wns + ni * 16 + l16) * 32 + q * 8];
    for (int mi = 0; mi < 4; ++mi)
      for (int ni = 0; ni < 4; ++ni)
        acc[mi][ni] = __builtin_amdgcn_mfma_f32_16x16x32_bf16(af[mi], bfr[ni], acc[mi][ni], 0, 0, 0);
  }
  for (int ni = 0; ni < 4; ++ni) {
    int s = s0 + wns + ni * 16 + l16;
    for (int mi = 0; mi < 4; ++mi) {
      int o0 = wmo + mi * 16 + q * 4;
      for (int r = 0; r < 4; ++r) {
        int o = o0 + r;
        out[(size_t)b * 2097152 + (size_t)o * 16384 + s] = acc[mi][ni][r] + misc[768 + o];
      }
    }
  }
}

extern "C" void kernel_launch(void* const* d_in, const int* in_sizes, int n_in,
                              void* d_out, int out_size, void* d_ws, size_t ws_size,
                              hipStream_t stream) {
  const float* x     = (const float*)d_in[0];
  const float* qkv_r = (const float*)d_in[1];
  const float* qkv_i = (const float*)d_in[2];
  const float* qkv_j = (const float*)d_in[3];
  const float* qkv_k = (const float*)d_in[4];
  const float* qkv_b = (const float*)d_in[5];
  const float* dw_r  = (const float*)d_in[6];
  const float* dw_i  = (const float*)d_in[7];
  const float* dw_j  = (const float*)d_in[8];
  const float* dw_k  = (const float*)d_in[9];
  const float* dw_b  = (const float*)d_in[10];
  const float* po_r  = (const float*)d_in[11];
  const float* po_i  = (const float*)d_in[12];
  const float* po_j  = (const float*)d_in[13];
  const float* po_k  = (const float*)d_in[14];
  const float* po_b  = (const float*)d_in[15];
  const float* temp  = (const float*)d_in[16];

  char* ws = (char*)d_ws;
  size_t off = 0;
  auto alloc = [&](size_t bytes) { char* p = ws + off; off += (bytes + 255) & ~(size_t)255; return p; };
  bf16* q1p  = (bf16*)alloc((size_t)2 * 130 * 130 * 384 * 2);
  bf16* q2   = (bf16*)alloc((size_t)2 * 16384 * 384 * 2);
  bf16* W1t  = (bf16*)alloc((size_t)384 * 128 * 2);
  bf16* W2t  = (bf16*)alloc((size_t)384 * 3456 * 2);
  bf16* W3t  = (bf16*)alloc((size_t)128 * 128 * 2);
  float* ssq  = (float*)alloc((size_t)2 * 256 * 4);
  float* Sraw = (float*)alloc((size_t)2 * 4 * 32 * 32 * 4);
  float* misc = (float*)alloc((size_t)900 * 4);

  prep<<<(N_PREP + 255) / 256, 256, 0, stream>>>(qkv_r, qkv_i, qkv_j, qkv_k,
                                                 dw_r, dw_i, dw_j, dw_k,
                                                 po_r, po_i, po_j, po_k,
                                                 qkv_b, dw_b, po_b, temp,
                                                 W1t, W2t, W3t, q1p, misc, ssq, Sraw);
  gemm_qkv1f<<<dim3(128, 2, 2), 256, 0, stream>>>(x, W1t, misc, q1p);
  conv3x3<<<768, 256, 0, stream>>>(q1p, W2t, misc + 384, q2);
  attn_qk<<<dim3(64, 4, 2), 256, 0, stream>>>(q2, Sraw, ssq);
  attn_out<<<256, 256, 0, stream>>>(q2, Sraw, ssq, misc, W3t, (float*)d_out);
}

// Round 8
// 237.328 us; speedup vs baseline: 1.1866x; 1.0191x over previous
//
#include <hip/hip_runtime.h>
#include <hip/hip_bf16.h>
#include <string.h>

typedef __hip_bfloat16 bf16;
typedef __bf16 bf16x8 __attribute__((ext_vector_type(8)));
typedef float f32x4 __attribute__((ext_vector_type(4)));

typedef __attribute__((address_space(1))) void* gas_ptr;
typedef __attribute__((address_space(3))) void* las_ptr;

__device__ __forceinline__ void gload_lds16(const void* g, void* l) {
  __builtin_amdgcn_global_load_lds((gas_ptr)(void*)g, (las_ptr)l, 16, 0, 0);
}

// Inputs confirmed fp32 (rounds 2-7 passed with fp32 path).

// ---------------- quaternion block expansion helper ----------------
__device__ __forceinline__ void qexpand(const float* r, const float* i_, const float* j_,
                                        const float* k_, bf16* dst, int O4, int I4, int taps,
                                        int gid) {
  int C = 4 * I4;
  int o   = gid / (taps * C);
  int rem = gid % (taps * C);
  int tap = rem / C, c = rem % C;
  int br = o / O4, orr = o % O4, bc = c / I4, ic = c % I4;
  const float* srcs[4] = { r, i_, j_, k_ };
  const int   comp[4][4] = { {0,1,2,3}, {1,0,3,2}, {2,3,0,1}, {3,2,1,0} };
  const float sgn [4][4] = { {1,-1,-1,-1}, {1,1,-1,1}, {1,1,1,-1}, {1,-1,1,1} };
  float v = srcs[comp[br][bc]][(size_t)(orr * I4 + ic) * taps + tap];
  dst[gid] = __float2bfloat16(v * sgn[br][bc]);
}

// ---------------- one prep kernel: weight expansion + misc cvt + all zero-inits ----------------
#define N_W1 49152
#define N_W2 1327104
#define N_W3 16384
#define N_BR 396288
#define N_MI 900
#define N_SQ 512
#define N_SR 8192
#define N_PREP (N_W1 + N_W2 + N_W3 + N_BR + N_MI + N_SQ + N_SR)

__global__ void prep(const float* __restrict__ qr, const float* __restrict__ qi,
                     const float* __restrict__ qj, const float* __restrict__ qk,
                     const float* __restrict__ dr, const float* __restrict__ di,
                     const float* __restrict__ dj, const float* __restrict__ dk,
                     const float* __restrict__ pr, const float* __restrict__ pi,
                     const float* __restrict__ pj, const float* __restrict__ pk,
                     const float* __restrict__ qb, const float* __restrict__ db,
                     const float* __restrict__ pb, const float* __restrict__ tp,
                     bf16* __restrict__ W1t, bf16* __restrict__ W2t, bf16* __restrict__ W3t,
                     bf16* __restrict__ q1p, float* __restrict__ misc,
                     float* __restrict__ ssq, float* __restrict__ Sraw) {
  int gid = blockIdx.x * 256 + threadIdx.x;
  if (gid < N_W1) { qexpand(qr, qi, qj, qk, W1t, 96, 32, 1, gid); return; }
  gid -= N_W1;
  if (gid < N_W2) { qexpand(dr, di, dj, dk, W2t, 96, 96, 9, gid); return; }
  gid -= N_W2;
  if (gid < N_W3) { qexpand(pr, pi, pj, pk, W3t, 32, 32, 1, gid); return; }
  gid -= N_W3;
  if (gid < N_BR) {
    int b = gid / (516 * 384);
    int rem = gid % (516 * 384);
    int cell = rem / 384, c = rem % 384;
    int hp, wp;
    if      (cell < 130) { hp = 0;   wp = cell; }
    else if (cell < 260) { hp = 129; wp = cell - 130; }
    else if (cell < 388) { hp = cell - 260 + 1; wp = 0; }
    else                 { hp = cell - 388 + 1; wp = 129; }
    q1p[((size_t)((b * 130 + hp) * 130) + wp) * 384 + c] = __float2bfloat16(0.0f);
    return;
  }
  gid -= N_BR;
  if (gid < N_MI) {
    if (gid < 384)      misc[gid] = qb[gid];
    else if (gid < 768) misc[gid] = db[gid - 384];
    else if (gid < 896) misc[gid] = pb[gid - 768];
    else                misc[gid] = tp[gid - 896];
    return;
  }
  gid -= N_MI;
  if (gid < N_SQ) { ssq[gid] = 0.0f; return; }
  gid -= N_SQ;
  if (gid < N_SR) { Sraw[gid] = 0.0f; return; }
}

// ---------------- GEMM1 fused: x NCHW fp32 -> LDS transpose -> 3 o-tiles; LDS-coalesced epilogue ----------------
__global__ __launch_bounds__(256) void gemm_qkv1f(const float* __restrict__ x,
                                                  const bf16* __restrict__ wt,
                                                  const float* __restrict__ bias,
                                                  bf16* __restrict__ out) {
  __shared__ __align__(16) bf16 Axl[4 * 64 * 32];   // [kchunk][w64][c32] 16 KB
  __shared__ __align__(16) bf16 Bl [4 * 128 * 32];  // [kchunk][o][c32]  32 KB (reused as epilogue tile)
  const int h = blockIdx.x, wh = blockIdx.y, b = blockIdx.z;
  const int tid = threadIdx.x, wid = tid >> 6, lane = tid & 63;
  const int l16 = lane & 15, q = lane >> 4;
  const int wm = (wid & 1) * 32, wn = (wid >> 1) * 64;
  {
    const int c = tid >> 1, seg = tid & 1;
    const float* src = x + ((size_t)(b * 128 + c) << 14) + h * 128 + wh * 64 + seg * 32;
    bf16* dstc = Axl + (c >> 5) * 2048 + (c & 31);
    for (int j = 0; j < 8; ++j) {
      float4 v = *(const float4*)(src + j * 4);
      int w0 = seg * 32 + j * 4;
      dstc[(w0 + 0) * 32] = __float2bfloat16(v.x);
      dstc[(w0 + 1) * 32] = __float2bfloat16(v.y);
      dstc[(w0 + 2) * 32] = __float2bfloat16(v.z);
      dstc[(w0 + 3) * 32] = __float2bfloat16(v.w);
    }
  }
  for (int ot = 0; ot < 3; ++ot) {
    __syncthreads();
    const bf16* bbase = wt + (size_t)ot * 16384;
    for (int i = 0; i < 8; ++i) {
      int ci = wid * 512 + i * 64 + lane;
      int chunk = ci >> 9, rem = ci & 511;
      int o = rem >> 2, part = rem & 3;
      gload_lds16(bbase + o * 128 + chunk * 32 + part * 8, Bl + (size_t)(wid * 512 + i * 64) * 8);
    }
    __syncthreads();
    f32x4 acc[2][4] = {};
    for (int k = 0; k < 4; ++k) {
      bf16x8 af[2], bfr[4];
      for (int mi = 0; mi < 2; ++mi)
        af[mi] = *(const bf16x8*)&Axl[k * 2048 + (wm + mi * 16 + l16) * 32 + q * 8];
      for (int ni = 0; ni < 4; ++ni)
        bfr[ni] = *(const bf16x8*)&Bl[k * 4096 + (wn + ni * 16 + l16) * 32 + q * 8];
      for (int mi = 0; mi < 2; ++mi)
        for (int ni = 0; ni < 4; ++ni)
          acc[mi][ni] = __builtin_amdgcn_mfma_f32_16x16x32_bf16(af[mi], bfr[ni], acc[mi][ni], 0, 0, 0);
    }
    // epilogue via LDS: tile [w64][o128], row stride 136 shorts (272B, 16B-aligned, bank-spread)
    __syncthreads();
    for (int ni = 0; ni < 4; ++ni) {
      int o = wn + ni * 16 + l16;
      float bv = bias[ot * 128 + o];
      for (int mi = 0; mi < 2; ++mi)
        for (int r = 0; r < 4; ++r) {
          int w = wm + mi * 16 + q * 4 + r;
          Bl[w * 136 + o] = __float2bfloat16(acc[mi][ni][r] + bv);
        }
    }
    __syncthreads();
    for (int i = 0; i < 4; ++i) {
      int idx = i * 256 + tid;              // 1024 chunks of 16B
      int row = idx >> 4, seg = idx & 15;   // row = w, 16 x 16B per row
      size_t gidx = ((size_t)((b * 130 + h + 1) * 130) + (wh * 64 + row + 1)) * 384 + ot * 128 + seg * 8;
      *(int4*)(out + gidx) = *(const int4*)&Bl[row * 136 + seg * 8];
    }
  }
}

// ---------------- conv2 v5: halo A reuse + LDS-coalesced epilogue ----------------
__global__ __launch_bounds__(256) void conv3x3(const bf16* __restrict__ in,
                                               const bf16* __restrict__ wt,
                                               const float* __restrict__ bias,
                                               bf16* __restrict__ out) {
  __shared__ __align__(16) short Al[6 * 66 * 32];   // 25344 B
  __shared__ __align__(16) short Bl[9 * 64 * 32];   // 36864 B (reused: 256 rows x 72 shorts epilogue)
  const int lid = blockIdx.x;
  const int xcd = lid & 7, slot = lid >> 3;
  const int b = xcd & 1;
  const int h0 = (xcd >> 1) * 32 + (slot & 7) * 4;
  const int wh = (slot >> 3) & 1;
  const int ob = (slot >> 4) * 64;
  const int tid = threadIdx.x, wid = tid >> 6, lane = tid & 63;
  const int l16 = lane & 15, q = lane >> 4;
  f32x4 acc[4][4] = {};
  const bf16* abase = in + (size_t)b * 130 * 130 * 384 + (size_t)wh * 64 * 384;
  const bf16* bbase = wt + (size_t)ob * 3456;
  for (int c0 = 0; c0 < 384; c0 += 32) {
    __syncthreads();
    for (int i = 0; i < 6; ++i) {
      int g = (wid * 6 + i) * 64;
      int ci = g + lane;
      int row = ci / 264, rem = ci % 264;
      int w = rem >> 2, part = rem & 3;
      gload_lds16(abase + ((size_t)(h0 + row) * 130 + w) * 384 + c0 + part * 8, &Al[g * 8]);
    }
    if (wid == 0 && lane < 48) {
      int ci = 1536 + lane;
      int row = ci / 264, rem = ci % 264;
      int w = rem >> 2, part = rem & 3;
      gload_lds16(abase + ((size_t)(h0 + row) * 130 + w) * 384 + c0 + part * 8, &Al[1536 * 8]);
    }
    for (int i = 0; i < 9; ++i) {
      int g = (wid * 9 + i) * 64;
      int ci = g + lane;
      int tap = ci >> 8, rem = ci & 255;
      int o = rem >> 2, part = rem & 3;
      gload_lds16(bbase + (size_t)o * 3456 + tap * 384 + c0 + part * 8, &Bl[g * 8]);
    }
    __syncthreads();
    for (int dh = 0; dh < 3; ++dh)
      for (int dw = 0; dw < 3; ++dw) {
        bf16x8 af[4], bfr[4];
        for (int mi = 0; mi < 4; ++mi)
          af[mi] = *(const bf16x8*)&Al[((wid + dh) * 66 + mi * 16 + l16 + dw) * 32 + q * 8];
        for (int ni = 0; ni < 4; ++ni)
          bfr[ni] = *(const bf16x8*)&Bl[((dh * 3 + dw) * 64 + ni * 16 + l16) * 32 + q * 8];
        for (int mi = 0; mi < 4; ++mi)
          for (int ni = 0; ni < 4; ++ni)
            acc[mi][ni] = __builtin_amdgcn_mfma_f32_16x16x32_bf16(af[mi], bfr[ni], acc[mi][ni], 0, 0, 0);
      }
  }
  // epilogue via LDS: 256 rows (4h x 64w) x 64o, row stride 72 shorts (144B)
  __syncthreads();
  {
    bf16* EB = (bf16*)Bl;
    for (int ni = 0; ni < 4; ++ni) {
      float bv = bias[ob + ni * 16 + l16];
      for (int mi = 0; mi < 4; ++mi)
        for (int r = 0; r < 4; ++r) {
          int w = mi * 16 + q * 4 + r;
          EB[(wid * 64 + w) * 72 + ni * 16 + l16] = __float2bfloat16(acc[mi][ni][r] + bv);
        }
    }
  }
  __syncthreads();
  for (int i = 0; i < 8; ++i) {
    int idx = i * 256 + tid;              // 2048 chunks of 16B
    int row = idx >> 3, seg = idx & 7;    // 8 x 16B per row
    int hh = row >> 6, w = row & 63;
    size_t s = (size_t)(b * 16384 + (h0 + hh) * 128 + wh * 64 + w);
    *(int4*)(out + s * 384 + ob + seg * 8) = *(const int4*)&Bl[row * 72 + seg * 8];
  }
}

// ---------------- attn_qk + fused channel ssq (LDS-reduced atomics) ----------------
__global__ __launch_bounds__(256) void attn_qk(const bf16* __restrict__ q2,
                                               float* __restrict__ Sraw,
                                               float* __restrict__ ssq) {
  const int sc = blockIdx.x, h = blockIdx.y, b = blockIdx.z;
  const int t = threadIdx.x;
  __shared__ bf16 qt[64][32];
  __shared__ bf16 kt[64][32];
  __shared__ float Sl[1024];
  __shared__ float nql[32], nkl[32];
  for (int i = t; i < 1024; i += 256) Sl[i] = 0.0f;
  if (t < 32) nql[t] = 0.0f;
  else if (t < 64) nkl[t - 32] = 0.0f;
  const int slq = t >> 2, seg = t & 3;
  const int slot = t & 63, sg = t >> 6;
  const int cg = (slot & 7) * 4, dg = (slot >> 3) * 4;
  float acc[4][4] = {};
  float sq[4] = {}, sk[4] = {};
  for (int it = 0; it < 8; ++it) {
    int sbase = sc * 512 + it * 64;
    __syncthreads();
    {
      size_t rq = ((size_t)(b * 16384 + sbase + slq)) * 384 + h * 32 + seg * 8;
      *(bf16x8*)&qt[slq][seg * 8] = *(const bf16x8*)&q2[rq];
      *(bf16x8*)&kt[slq][seg * 8] = *(const bf16x8*)&q2[rq + 128];
    }
    __syncthreads();
    for (int sl = sg * 16; sl < sg * 16 + 16; ++sl) {
      float qv[4], kv[4];
      for (int a = 0; a < 4; ++a) qv[a] = __bfloat162float(qt[sl][cg + a]);
      for (int d = 0; d < 4; ++d) kv[d] = __bfloat162float(kt[sl][dg + d]);
      if (dg == 0) for (int a = 0; a < 4; ++a) sq[a] += qv[a] * qv[a];
      if (cg == 0) for (int d = 0; d < 4; ++d) sk[d] += kv[d] * kv[d];
      for (int a = 0; a < 4; ++a)
        for (int d = 0; d < 4; ++d) acc[a][d] += qv[a] * kv[d];
    }
  }
  for (int a = 0; a < 4; ++a)
    for (int d = 0; d < 4; ++d)
      atomicAdd(&Sl[(cg + a) * 32 + dg + d], acc[a][d]);
  if (dg == 0) for (int a = 0; a < 4; ++a) atomicAdd(&nql[cg + a], sq[a]);
  if (cg == 0) for (int d = 0; d < 4; ++d) atomicAdd(&nkl[dg + d], sk[d]);
  __syncthreads();
  float* Sg = Sraw + (size_t)((b * 4 + h) * 1024);
  for (int i = t * 4; i < t * 4 + 4; ++i) atomicAdd(&Sg[i], Sl[i]);
  if (t < 32) atomicAdd(&ssq[b * 256 + h * 32 + t], nql[t]);
  else if (t < 64) atomicAdd(&ssq[b * 256 + 128 + h * 32 + (t - 32)], nkl[t - 32]);
}

// ---------------- attn_out: softmax -> M = W3.blockdiag(P) in LDS -> GEMM vs v -> d_out ----------------
__global__ __launch_bounds__(256) void attn_out(const bf16* __restrict__ q2,
                                                const float* __restrict__ Sraw,
                                                const float* __restrict__ ssq,
                                                const float* __restrict__ misc,
                                                const bf16* __restrict__ w3,
                                                float* __restrict__ out) {
  __shared__ __align__(16) bf16 Ml[4 * 128 * 32];   // 32 KB [kchunk][o][c31]
  __shared__ float Pl[4][32][32];                    // 16 KB
  __shared__ __align__(16) short Bl[128 * 32];       // 8 KB v-stage
  __shared__ float rqa[128], rka[128];
  const int tile = blockIdx.x;
  const int b = tile >> 7, s0 = (tile & 127) * 128;
  const int t = threadIdx.x;
  const int wid = t >> 6, lane = t & 63;
  const int l16 = lane & 15, q = lane >> 4;
  {
    float v = ssq[b * 256 + t];
    float rv = 1.0f / fmaxf(sqrtf(fmaxf(v, 0.0f)), 1e-12f);
    if (t < 128) rqa[t] = rv; else rka[t - 128] = rv;
  }
  __syncthreads();
  if (t < 128) {
    int hh = t >> 5, c = t & 31;
    const float* Sr = Sraw + ((size_t)((b * 4 + hh) * 32 + c)) * 32;
    float tv = misc[896 + hh];
    float rq = rqa[t];
    float row[32];
    float m = -1e30f;
    for (int d = 0; d < 32; ++d) { row[d] = Sr[d] * tv * rq * rka[hh * 32 + d]; m = fmaxf(m, row[d]); }
    float sum = 0.0f;
    for (int d = 0; d < 32; ++d) { row[d] = expf(row[d] - m); sum += row[d]; }
    float inv = 1.0f / sum;
    for (int d = 0; d < 32; ++d) Pl[hh][c][d] = row[d] * inv;
  }
  __syncthreads();
  {
    const int o = t >> 1, half = t & 1;
    for (int hh2 = 0; hh2 < 2; ++hh2) {
      int hv = half * 2 + hh2;
      float w3r[32];
      const bf16* wrow = w3 + o * 128 + hv * 32;
      for (int c = 0; c < 32; ++c) w3r[c] = __bfloat162float(wrow[c]);
      for (int d = 0; d < 32; ++d) {
        float s = 0.0f;
        for (int c = 0; c < 32; ++c) s += w3r[c] * Pl[hv][c][d];
        Ml[hv * 4096 + o * 32 + d] = __float2bfloat16(s);
      }
    }
  }
  f32x4 acc[4][4] = {};
  const int wmo = (wid & 1) * 64, wns = (wid >> 1) * 64;
  for (int kc = 0; kc < 4; ++kc) {
    __syncthreads();
    for (int i = 0; i < 2; ++i) {
      int ci = i * 256 + t;                         // t = wid*64 + lane
      int s = ci >> 2, part = ci & 3;
      gload_lds16(q2 + ((size_t)(b * 16384 + s0 + s)) * 384 + 256 + kc * 32 + part * 8,
                  &Bl[(size_t)(i * 256 + wid * 64) * 8]);
    }
    __syncthreads();
    bf16x8 af[4], bfr[4];
    for (int mi = 0; mi < 4; ++mi)
      af[mi] = *(const bf16x8*)&Ml[kc * 4096 + (wmo + mi * 16 + l16) * 32 + q * 8];
    for (int ni = 0; ni < 4; ++ni)
      bfr[ni] = *(const bf16x8*)&Bl[(wns + ni * 16 + l16) * 32 + q * 8];
    for (int mi = 0; mi < 4; ++mi)
      for (int ni = 0; ni < 4; ++ni)
        acc[mi][ni] = __builtin_amdgcn_mfma_f32_16x16x32_bf16(af[mi], bfr[ni], acc[mi][ni], 0, 0, 0);
  }
  for (int ni = 0; ni < 4; ++ni) {
    int s = s0 + wns + ni * 16 + l16;
    for (int mi = 0; mi < 4; ++mi) {
      int o0 = wmo + mi * 16 + q * 4;
      for (int r = 0; r < 4; ++r) {
        int o = o0 + r;
        out[(size_t)b * 2097152 + (size_t)o * 16384 + s] = acc[mi][ni][r] + misc[768 + o];
      }
    }
  }
}

extern "C" void kernel_launch(void* const* d_in, const int* in_sizes, int n_in,
                              void* d_out, int out_size, void* d_ws, size_t ws_size,
                              hipStream_t stream) {
  const float* x     = (const float*)d_in[0];
  const float* qkv_r = (const float*)d_in[1];
  const float* qkv_i = (const float*)d_in[2];
  const float* qkv_j = (const float*)d_in[3];
  const float* qkv_k = (const float*)d_in[4];
  const float* qkv_b = (const float*)d_in[5];
  const float* dw_r  = (const float*)d_in[6];
  const float* dw_i  = (const float*)d_in[7];
  const float* dw_j  = (const float*)d_in[8];
  const float* dw_k  = (const float*)d_in[9];
  const float* dw_b  = (const float*)d_in[10];
  const float* po_r  = (const float*)d_in[11];
  const float* po_i  = (const float*)d_in[12];
  const float* po_j  = (const float*)d_in[13];
  const float* po_k  = (const float*)d_in[14];
  const float* po_b  = (const float*)d_in[15];
  const float* temp  = (const float*)d_in[16];

  char* ws = (char*)d_ws;
  size_t off = 0;
  auto alloc = [&](size_t bytes) { char* p = ws + off; off += (bytes + 255) & ~(size_t)255; return p; };
  bf16* q1p  = (bf16*)alloc((size_t)2 * 130 * 130 * 384 * 2);
  bf16* q2   = (bf16*)alloc((size_t)2 * 16384 * 384 * 2);
  bf16* W1t  = (bf16*)alloc((size_t)384 * 128 * 2);
  bf16* W2t  = (bf16*)alloc((size_t)384 * 3456 * 2);
  bf16* W3t  = (bf16*)alloc((size_t)128 * 128 * 2);
  float* ssq  = (float*)alloc((size_t)2 * 256 * 4);
  float* Sraw = (float*)alloc((size_t)2 * 4 * 32 * 32 * 4);
  float* misc = (float*)alloc((size_t)900 * 4);

  prep<<<(N_PREP + 255) / 256, 256, 0, stream>>>(qkv_r, qkv_i, qkv_j, qkv_k,
                                                 dw_r, dw_i, dw_j, dw_k,
                                                 po_r, po_i, po_j, po_k,
                                                 qkv_b, dw_b, po_b, temp,
                                                 W1t, W2t, W3t, q1p, misc, ssq, Sraw);
  gemm_qkv1f<<<dim3(128, 2, 2), 256, 0, stream>>>(x, W1t, misc, q1p);
  conv3x3<<<768, 256, 0, stream>>>(q1p, W2t, misc + 384, q2);
  attn_qk<<<dim3(32, 4, 2), 256, 0, stream>>>(q2, Sraw, ssq);
  attn_out<<<256, 256, 0, stream>>>(q2, Sraw, ssq, misc, W3t, (float*)d_out);
}

// Round 9
// 229.489 us; speedup vs baseline: 1.2271x; 1.0342x over previous
//
#include <hip/hip_runtime.h>
#include <hip/hip_bf16.h>
#include <string.h>

typedef __hip_bfloat16 bf16;
typedef __bf16 bf16x8 __attribute__((ext_vector_type(8)));
typedef float f32x4 __attribute__((ext_vector_type(4)));

typedef __attribute__((address_space(1))) void* gas_ptr;
typedef __attribute__((address_space(3))) void* las_ptr;

__device__ __forceinline__ void gload_lds16(const void* g, void* l) {
  __builtin_amdgcn_global_load_lds((gas_ptr)(void*)g, (las_ptr)l, 16, 0, 0);
}

// Inputs confirmed fp32 (rounds 2-8 passed with fp32 path).

// ---------------- quaternion block expansion helper ----------------
__device__ __forceinline__ void qexpand(const float* r, const float* i_, const float* j_,
                                        const float* k_, bf16* dst, int O4, int I4, int taps,
                                        int gid) {
  int C = 4 * I4;
  int o   = gid / (taps * C);
  int rem = gid % (taps * C);
  int tap = rem / C, c = rem % C;
  int br = o / O4, orr = o % O4, bc = c / I4, ic = c % I4;
  const float* srcs[4] = { r, i_, j_, k_ };
  const int   comp[4][4] = { {0,1,2,3}, {1,0,3,2}, {2,3,0,1}, {3,2,1,0} };
  const float sgn [4][4] = { {1,-1,-1,-1}, {1,1,-1,1}, {1,1,1,-1}, {1,-1,1,1} };
  float v = srcs[comp[br][bc]][(size_t)(orr * I4 + ic) * taps + tap];
  dst[gid] = __float2bfloat16(v * sgn[br][bc]);
}

// ---------------- one prep kernel: weight expansion + misc cvt + all zero-inits ----------------
#define N_W1 49152
#define N_W2 1327104
#define N_W3 16384
#define N_BR 396288
#define N_MI 900
#define N_SQ 512
#define N_SR 8192
#define N_PREP (N_W1 + N_W2 + N_W3 + N_BR + N_MI + N_SQ + N_SR)

__global__ void prep(const float* __restrict__ qr, const float* __restrict__ qi,
                     const float* __restrict__ qj, const float* __restrict__ qk,
                     const float* __restrict__ dr, const float* __restrict__ di,
                     const float* __restrict__ dj, const float* __restrict__ dk,
                     const float* __restrict__ pr, const float* __restrict__ pi,
                     const float* __restrict__ pj, const float* __restrict__ pk,
                     const float* __restrict__ qb, const float* __restrict__ db,
                     const float* __restrict__ pb, const float* __restrict__ tp,
                     bf16* __restrict__ W1t, bf16* __restrict__ W2t, bf16* __restrict__ W3t,
                     bf16* __restrict__ q1p, float* __restrict__ misc,
                     float* __restrict__ ssq, float* __restrict__ Sraw) {
  int gid = blockIdx.x * 256 + threadIdx.x;
  if (gid < N_W1) { qexpand(qr, qi, qj, qk, W1t, 96, 32, 1, gid); return; }
  gid -= N_W1;
  if (gid < N_W2) { qexpand(dr, di, dj, dk, W2t, 96, 96, 9, gid); return; }
  gid -= N_W2;
  if (gid < N_W3) { qexpand(pr, pi, pj, pk, W3t, 32, 32, 1, gid); return; }
  gid -= N_W3;
  if (gid < N_BR) {
    int b = gid / (516 * 384);
    int rem = gid % (516 * 384);
    int cell = rem / 384, c = rem % 384;
    int hp, wp;
    if      (cell < 130) { hp = 0;   wp = cell; }
    else if (cell < 260) { hp = 129; wp = cell - 130; }
    else if (cell < 388) { hp = cell - 260 + 1; wp = 0; }
    else                 { hp = cell - 388 + 1; wp = 129; }
    q1p[((size_t)((b * 130 + hp) * 130) + wp) * 384 + c] = __float2bfloat16(0.0f);
    return;
  }
  gid -= N_BR;
  if (gid < N_MI) {
    if (gid < 384)      misc[gid] = qb[gid];
    else if (gid < 768) misc[gid] = db[gid - 384];
    else if (gid < 896) misc[gid] = pb[gid - 768];
    else                misc[gid] = tp[gid - 896];
    return;
  }
  gid -= N_MI;
  if (gid < N_SQ) { ssq[gid] = 0.0f; return; }
  gid -= N_SQ;
  if (gid < N_SR) { Sraw[gid] = 0.0f; return; }
}

// ---------------- GEMM1 fused: x NCHW fp32 -> LDS transpose -> 3 o-tiles ----------------
__global__ __launch_bounds__(256) void gemm_qkv1f(const float* __restrict__ x,
                                                  const bf16* __restrict__ wt,
                                                  const float* __restrict__ bias,
                                                  bf16* __restrict__ out) {
  __shared__ __align__(16) bf16 Axl[4 * 64 * 32];   // [kchunk][w64][c32] 16 KB
  __shared__ __align__(16) bf16 Bl [4 * 128 * 32];  // [kchunk][o][c32]  32 KB
  const int h = blockIdx.x, wh = blockIdx.y, b = blockIdx.z;
  const int tid = threadIdx.x, wid = tid >> 6, lane = tid & 63;
  const int l16 = lane & 15, q = lane >> 4;
  const int wm = (wid & 1) * 32, wn = (wid >> 1) * 64;
  {
    const int c = tid >> 1, seg = tid & 1;
    const float* src = x + ((size_t)(b * 128 + c) << 14) + h * 128 + wh * 64 + seg * 32;
    bf16* dstc = Axl + (c >> 5) * 2048 + (c & 31);
    for (int j = 0; j < 8; ++j) {
      float4 v = *(const float4*)(src + j * 4);
      int w0 = seg * 32 + j * 4;
      dstc[(w0 + 0) * 32] = __float2bfloat16(v.x);
      dstc[(w0 + 1) * 32] = __float2bfloat16(v.y);
      dstc[(w0 + 2) * 32] = __float2bfloat16(v.z);
      dstc[(w0 + 3) * 32] = __float2bfloat16(v.w);
    }
  }
  for (int ot = 0; ot < 3; ++ot) {
    __syncthreads();
    const bf16* bbase = wt + (size_t)ot * 16384;
    for (int i = 0; i < 8; ++i) {
      int ci = wid * 512 + i * 64 + lane;
      int chunk = ci >> 9, rem = ci & 511;
      int o = rem >> 2, part = rem & 3;
      gload_lds16(bbase + o * 128 + chunk * 32 + part * 8, Bl + (size_t)(wid * 512 + i * 64) * 8);
    }
    __syncthreads();
    f32x4 acc[2][4] = {};
    for (int k = 0; k < 4; ++k) {
      bf16x8 af[2], bfr[4];
      for (int mi = 0; mi < 2; ++mi)
        af[mi] = *(const bf16x8*)&Axl[k * 2048 + (wm + mi * 16 + l16) * 32 + q * 8];
      for (int ni = 0; ni < 4; ++ni)
        bfr[ni] = *(const bf16x8*)&Bl[k * 4096 + (wn + ni * 16 + l16) * 32 + q * 8];
      for (int mi = 0; mi < 2; ++mi)
        for (int ni = 0; ni < 4; ++ni)
          acc[mi][ni] = __builtin_amdgcn_mfma_f32_16x16x32_bf16(af[mi], bfr[ni], acc[mi][ni], 0, 0, 0);
    }
    for (int ni = 0; ni < 4; ++ni) {
      int o = ot * 128 + wn + ni * 16 + l16;
      float bv = bias[o];
      for (int mi = 0; mi < 2; ++mi) {
        int w0 = wh * 64 + wm + mi * 16 + q * 4;
        for (int r = 0; r < 4; ++r) {
          int w = w0 + r;
          size_t idx = ((size_t)((b * 130 + h + 1) * 130) + (w + 1)) * 384 + o;
          out[idx] = __float2bfloat16(acc[mi][ni][r] + bv);
        }
      }
    }
    __syncthreads();
  }
}

// ---------------- conv2 v6: zero-tail grid 512 (2 blocks/CU, all resident) ----------------
// xcd=lid&7 -> b=xcd&1, hband=(xcd>>1)*32; slot=lid>>3 in [0,64):
//   h0 = hband + (slot&7)*4 (4 h-rows, one per wave), ob = (slot>>3)*48 (48-o slice), full 128 w.
// Per c0 (12 stages): A = 6 padded rows x 132 w x 32c (50.7 KB; cols 130,131 are in-bounds garbage,
// never consumed), B = 9 taps x 48 o x 32c (27.6 KB). 216 MFMA/wave/stage.
__global__ __launch_bounds__(256, 2) void conv3x3(const bf16* __restrict__ in,
                                                  const bf16* __restrict__ wt,
                                                  const float* __restrict__ bias,
                                                  bf16* __restrict__ out) {
  __shared__ __align__(16) short Al[6 * 132 * 32];   // 50688 B, chunk-contiguous
  __shared__ __align__(16) short Bl[9 * 48 * 32];    // 27648 B
  const int lid = blockIdx.x;
  const int xcd = lid & 7, slot = lid >> 3;
  const int b = xcd & 1;
  const int h0 = (xcd >> 1) * 32 + (slot & 7) * 4;
  const int ob = (slot >> 3) * 48;
  const int tid = threadIdx.x, wid = tid >> 6, lane = tid & 63;
  const int l16 = lane & 15, q = lane >> 4;
  f32x4 acc[8][3] = {};
  const bf16* abase = in + (size_t)b * 130 * 130 * 384;
  const bf16* bbase = wt + (size_t)ob * 3456;
  for (int c0 = 0; c0 < 384; c0 += 32) {
    __syncthreads();
    // A: 3168 chunks (6 rows x 132 w x 4 parts); 792/wave = 12x64 + 24
    for (int i = 0; i < 12; ++i) {
      int g = wid * 792 + i * 64;
      int ci = g + lane;
      int row = ci / 528, rem = ci % 528;
      int w = rem >> 2, part = rem & 3;
      gload_lds16(abase + ((size_t)(h0 + row) * 130 + w) * 384 + c0 + part * 8, &Al[g * 8]);
    }
    if (lane < 24) {
      int g = wid * 792 + 768;
      int ci = g + lane;
      int row = ci / 528, rem = ci % 528;
      int w = rem >> 2, part = rem & 3;
      gload_lds16(abase + ((size_t)(h0 + row) * 130 + w) * 384 + c0 + part * 8, &Al[g * 8]);
    }
    // B: 1728 chunks (9 taps x 48 o x 4 parts); 432/wave = 6x64 + 48
    for (int i = 0; i < 6; ++i) {
      int g = wid * 432 + i * 64;
      int ci = g + lane;
      int tap = ci / 192, rem = ci % 192;
      int o = rem >> 2, part = rem & 3;
      gload_lds16(bbase + (size_t)o * 3456 + tap * 384 + c0 + part * 8, &Bl[g * 8]);
    }
    if (lane < 48) {
      int g = wid * 432 + 384;
      int ci = g + lane;
      int tap = ci / 192, rem = ci % 192;
      int o = rem >> 2, part = rem & 3;
      gload_lds16(bbase + (size_t)o * 3456 + tap * 384 + c0 + part * 8, &Bl[g * 8]);
    }
    __syncthreads();
    for (int dh = 0; dh < 3; ++dh)
      for (int dw = 0; dw < 3; ++dw) {
        bf16x8 af[8], bfr[3];
        for (int mi = 0; mi < 8; ++mi)
          af[mi] = *(const bf16x8*)&Al[((wid + dh) * 132 + mi * 16 + l16 + dw) * 32 + q * 8];
        for (int ni = 0; ni < 3; ++ni)
          bfr[ni] = *(const bf16x8*)&Bl[((dh * 3 + dw) * 48 + ni * 16 + l16) * 32 + q * 8];
        for (int mi = 0; mi < 8; ++mi)
          for (int ni = 0; ni < 3; ++ni)
            acc[mi][ni] = __builtin_amdgcn_mfma_f32_16x16x32_bf16(af[mi], bfr[ni], acc[mi][ni], 0, 0, 0);
      }
  }
  const int h = h0 + wid;
  for (int ni = 0; ni < 3; ++ni) {
    int o = ob + ni * 16 + l16;
    float bv = bias[o];
    for (int mi = 0; mi < 8; ++mi) {
      int w0 = mi * 16 + q * 4;
      for (int r = 0; r < 4; ++r) {
        int w = w0 + r;
        out[((size_t)(b * 16384 + h * 128 + w)) * 384 + o] = __float2bfloat16(acc[mi][ni][r] + bv);
      }
    }
  }
}

// ---------------- attn_qk + fused channel ssq (LDS-reduced atomics) ----------------
__global__ __launch_bounds__(256) void attn_qk(const bf16* __restrict__ q2,
                                               float* __restrict__ Sraw,
                                               float* __restrict__ ssq) {
  const int sc = blockIdx.x, h = blockIdx.y, b = blockIdx.z;
  const int t = threadIdx.x;
  __shared__ bf16 qt[64][32];
  __shared__ bf16 kt[64][32];
  __shared__ float Sl[1024];
  __shared__ float nql[32], nkl[32];
  for (int i = t; i < 1024; i += 256) Sl[i] = 0.0f;
  if (t < 32) nql[t] = 0.0f;
  else if (t < 64) nkl[t - 32] = 0.0f;
  const int slq = t >> 2, seg = t & 3;
  const int slot = t & 63, sg = t >> 6;
  const int cg = (slot & 7) * 4, dg = (slot >> 3) * 4;
  float acc[4][4] = {};
  float sq[4] = {}, sk[4] = {};
  for (int it = 0; it < 8; ++it) {
    int sbase = sc * 512 + it * 64;
    __syncthreads();
    {
      size_t rq = ((size_t)(b * 16384 + sbase + slq)) * 384 + h * 32 + seg * 8;
      *(bf16x8*)&qt[slq][seg * 8] = *(const bf16x8*)&q2[rq];
      *(bf16x8*)&kt[slq][seg * 8] = *(const bf16x8*)&q2[rq + 128];
    }
    __syncthreads();
    for (int sl = sg * 16; sl < sg * 16 + 16; ++sl) {
      float qv[4], kv[4];
      for (int a = 0; a < 4; ++a) qv[a] = __bfloat162float(qt[sl][cg + a]);
      for (int d = 0; d < 4; ++d) kv[d] = __bfloat162float(kt[sl][dg + d]);
      if (dg == 0) for (int a = 0; a < 4; ++a) sq[a] += qv[a] * qv[a];
      if (cg == 0) for (int d = 0; d < 4; ++d) sk[d] += kv[d] * kv[d];
      for (int a = 0; a < 4; ++a)
        for (int d = 0; d < 4; ++d) acc[a][d] += qv[a] * kv[d];
    }
  }
  for (int a = 0; a < 4; ++a)
    for (int d = 0; d < 4; ++d)
      atomicAdd(&Sl[(cg + a) * 32 + dg + d], acc[a][d]);
  if (dg == 0) for (int a = 0; a < 4; ++a) atomicAdd(&nql[cg + a], sq[a]);
  if (cg == 0) for (int d = 0; d < 4; ++d) atomicAdd(&nkl[dg + d], sk[d]);
  __syncthreads();
  float* Sg = Sraw + (size_t)((b * 4 + h) * 1024);
  for (int i = t * 4; i < t * 4 + 4; ++i) atomicAdd(&Sg[i], Sl[i]);
  if (t < 32) atomicAdd(&ssq[b * 256 + h * 32 + t], nql[t]);
  else if (t < 64) atomicAdd(&ssq[b * 256 + 128 + h * 32 + (t - 32)], nkl[t - 32]);
}

// ---------------- attn_out: softmax -> M = W3.blockdiag(P) in LDS -> GEMM vs v -> d_out ----------------
__global__ __launch_bounds__(256) void attn_out(const bf16* __restrict__ q2,
                                                const float* __restrict__ Sraw,
                                                const float* __restrict__ ssq,
                                                const float* __restrict__ misc,
                                                const bf16* __restrict__ w3,
                                                float* __restrict__ out) {
  __shared__ __align__(16) bf16 Ml[4 * 128 * 32];   // 32 KB [kchunk][o][c31]
  __shared__ float Pl[4][32][32];                    // 16 KB
  __shared__ __align__(16) short Bl[128 * 32];       // 8 KB v-stage
  __shared__ float rqa[128], rka[128];
  const int tile = blockIdx.x;
  const int b = tile >> 7, s0 = (tile & 127) * 128;
  const int t = threadIdx.x;
  const int wid = t >> 6, lane = t & 63;
  const int l16 = lane & 15, q = lane >> 4;
  {
    float v = ssq[b * 256 + t];
    float rv = 1.0f / fmaxf(sqrtf(fmaxf(v, 0.0f)), 1e-12f);
    if (t < 128) rqa[t] = rv; else rka[t - 128] = rv;
  }
  __syncthreads();
  if (t < 128) {
    int hh = t >> 5, c = t & 31;
    const float* Sr = Sraw + ((size_t)((b * 4 + hh) * 32 + c)) * 32;
    float tv = misc[896 + hh];
    float rq = rqa[t];
    float row[32];
    float m = -1e30f;
    for (int d = 0; d < 32; ++d) { row[d] = Sr[d] * tv * rq * rka[hh * 32 + d]; m = fmaxf(m, row[d]); }
    float sum = 0.0f;
    for (int d = 0; d < 32; ++d) { row[d] = expf(row[d] - m); sum += row[d]; }
    float inv = 1.0f / sum;
    for (int d = 0; d < 32; ++d) Pl[hh][c][d] = row[d] * inv;
  }
  __syncthreads();
  {
    const int o = t >> 1, half = t & 1;
    for (int hh2 = 0; hh2 < 2; ++hh2) {
      int hv = half * 2 + hh2;
      float w3r[32];
      const bf16* wrow = w3 + o * 128 + hv * 32;
      for (int c = 0; c < 32; ++c) w3r[c] = __bfloat162float(wrow[c]);
      for (int d = 0; d < 32; ++d) {
        float s = 0.0f;
        for (int c = 0; c < 32; ++c) s += w3r[c] * Pl[hv][c][d];
        Ml[hv * 4096 + o * 32 + d] = __float2bfloat16(s);
      }
    }
  }
  f32x4 acc[4][4] = {};
  const int wmo = (wid & 1) * 64, wns = (wid >> 1) * 64;
  for (int kc = 0; kc < 4; ++kc) {
    __syncthreads();
    for (int i = 0; i < 2; ++i) {
      int ci = i * 256 + t;
      int s = ci >> 2, part = ci & 3;
      gload_lds16(q2 + ((size_t)(b * 16384 + s0 + s)) * 384 + 256 + kc * 32 + part * 8,
                  &Bl[(size_t)(i * 256 + wid * 64) * 8]);
    }
    __syncthreads();
    bf16x8 af[4], bfr[4];
    for (int mi = 0; mi < 4; ++mi)
      af[mi] = *(const bf16x8*)&Ml[kc * 4096 + (wmo + mi * 16 + l16) * 32 + q * 8];
    for (int ni = 0; ni < 4; ++ni)
      bfr[ni] = *(const bf16x8*)&Bl[(wns + ni * 16 + l16) * 32 + q * 8];
    for (int mi = 0; mi < 4; ++mi)
      for (int ni = 0; ni < 4; ++ni)
        acc[mi][ni] = __builtin_amdgcn_mfma_f32_16x16x32_bf16(af[mi], bfr[ni], acc[mi][ni], 0, 0, 0);
  }
  for (int ni = 0; ni < 4; ++ni) {
    int s = s0 + wns + ni * 16 + l16;
    for (int mi = 0; mi < 4; ++mi) {
      int o0 = wmo + mi * 16 + q * 4;
      for (int r = 0; r < 4; ++r) {
        int o = o0 + r;
        out[(size_t)b * 2097152 + (size_t)o * 16384 + s] = acc[mi][ni][r] + misc[768 + o];
      }
    }
  }
}

extern "C" void kernel_launch(void* const* d_in, const int* in_sizes, int n_in,
                              void* d_out, int out_size, void* d_ws, size_t ws_size,
                              hipStream_t stream) {
  const float* x     = (const float*)d_in[0];
  const float* qkv_r = (const float*)d_in[1];
  const float* qkv_i = (const float*)d_in[2];
  const float* qkv_j = (const float*)d_in[3];
  const float* qkv_k = (const float*)d_in[4];
  const float* qkv_b = (const float*)d_in[5];
  const float* dw_r  = (const float*)d_in[6];
  const float* dw_i  = (const float*)d_in[7];
  const float* dw_j  = (const float*)d_in[8];
  const float* dw_k  = (const float*)d_in[9];
  const float* dw_b  = (const float*)d_in[10];
  const float* po_r  = (const float*)d_in[11];
  const float* po_i  = (const float*)d_in[12];
  const float* po_j  = (const float*)d_in[13];
  const float* po_k  = (const float*)d_in[14];
  const float* po_b  = (const float*)d_in[15];
  const float* temp  = (const float*)d_in[16];

  char* ws = (char*)d_ws;
  size_t off = 0;
  auto alloc = [&](size_t bytes) { char* p = ws + off; off += (bytes + 255) & ~(size_t)255; return p; };
  bf16* q1p  = (bf16*)alloc((size_t)2 * 130 * 130 * 384 * 2);
  bf16* q2   = (bf16*)alloc((size_t)2 * 16384 * 384 * 2);
  bf16* W1t  = (bf16*)alloc((size_t)384 * 128 * 2);
  bf16* W2t  = (bf16*)alloc((size_t)384 * 3456 * 2);
  bf16* W3t  = (bf16*)alloc((size_t)128 * 128 * 2);
  float* ssq  = (float*)alloc((size_t)2 * 256 * 4);
  float* Sraw = (float*)alloc((size_t)2 * 4 * 32 * 32 * 4);
  float* misc = (float*)alloc((size_t)900 * 4);

  prep<<<(N_PREP + 255) / 256, 256, 0, stream>>>(qkv_r, qkv_i, qkv_j, qkv_k,
                                                 dw_r, dw_i, dw_j, dw_k,
                                                 po_r, po_i, po_j, po_k,
                                                 qkv_b, dw_b, po_b, temp,
                                                 W1t, W2t, W3t, q1p, misc, ssq, Sraw);
  gemm_qkv1f<<<dim3(128, 2, 2), 256, 0, stream>>>(x, W1t, misc, q1p);
  conv3x3<<<512, 256, 0, stream>>>(q1p, W2t, misc + 384, q2);
  attn_qk<<<dim3(32, 4, 2), 256, 0, stream>>>(q2, Sraw, ssq);
  attn_out<<<256, 256, 0, stream>>>(q2, Sraw, ssq, misc, W3t, (float*)d_out);
}